// Round 14
// baseline (270.826 us; speedup 1.0000x reference)
//
#include <hip/hip_runtime.h>

// Problem constants (fixed by the reference)
#define BATCH   8192
#define GROUPS  512
#define ARITY   3
#define OUT_DIM 16
#define NV      27          // 3^3 vertices
#define XCOLS   (GROUPS*ARITY)      // 1536
#define OCOLS   (GROUPS*OUT_DIM)    // 8192

// R14 = R11 (best, 60.0us) x NREP=5 identical passes — DIAGNOSTIC ROUND.
// Output is rewritten with identical values each pass (deterministic,
// validates). Purpose: make the dispatch ~300us so it appears in the
// rocprof top-5 with its own counters (at 60us it is always shorter than
// the harness's ~155us fill kernels, so its hbm_pct/VALUBusy/Occupancy
// have never been observed). Access pattern per pass identical to
// production (same 5:1 write:read ratio, same nt stream, same grid).
#define BTILE 32
#define NCHUNK 4
#define NREP 5
#define GTILE 16
#define PSTRIDE 444     // bf16 elems per group (432 + 12 pad)

typedef float    f32x4 __attribute__((ext_vector_type(4)));
typedef unsigned u32x2 __attribute__((ext_vector_type(2)));

__device__ __forceinline__ unsigned cvt_pk_bf16(float lo, float hi) {
    unsigned r;
    asm("v_cvt_pk_bf16_f32 %0, %1, %2" : "=v"(r) : "v"(lo), "v"(hi));
    return r;
}
__device__ __forceinline__ float bflo(unsigned u) {
    union { unsigned u; float f; } c; c.u = u << 16; return c.f;
}
__device__ __forceinline__ float bfhi(unsigned u) {
    union { unsigned u; float f; } c; c.u = u & 0xffff0000u; return c.f;
}

__global__ __launch_bounds__(256, 8) void lattice_interp_kernel(
    const float* __restrict__ X,
    const float* __restrict__ P,
    float* __restrict__ out)
{
    __shared__ float xs[BTILE * GTILE * ARITY];        // 1536 f32 = 6144 B
    __shared__ unsigned short ps[GTILE * PSTRIDE];     // 7104 bf16 = 14208 B

    const int t  = threadIdx.x;
    const int g0 = blockIdx.x * GTILE;              // group chunk: FAST dim
    const int bbase = blockIdx.y * (BTILE * NCHUNK); // 128-batch span: SLOW

    // ---- stage params for 16 groups as bf16 (ONCE per block)
    {
        const float4* src = reinterpret_cast<const float4*>(P + (size_t)g0 * (NV * OUT_DIM));
        #pragma unroll
        for (int k = 0; k < 7; ++k) {
            const int f = t + k * 256;
            if (f < 1728) {
                const float4 v = src[f];
                const int pgl = f / 108;          // 108 float4 per group
                const int rem = f - pgl * 108;
                u32x2 w;
                w.x = cvt_pk_bf16(v.x, v.y);
                w.y = cvt_pk_bf16(v.z, v.w);
                *reinterpret_cast<u32x2*>(&ps[pgl * PSTRIDE + rem * 4]) = w;
            }
        }
    }

    const int wv = t >> 6;
    const int l  = t & 63;
    const int gl = l >> 2;    // group-local 0..15
    const int oq = l & 3;     // which float4 of the 16 outputs

    const unsigned short* pbase = ps + gl * PSTRIDE + oq * 4;  // + vb*16 at runtime
    const float* xb = xs + gl * ARITY;

    #pragma unroll 1
    for (int rep = 0; rep < NREP; ++rep) {

        // ---- stage X chunk 0: rows [bbase, bbase+32) cols [g0*3, g0*3+48)
        {
            const float* src_base = X + (size_t)bbase * XCOLS + g0 * ARITY;
            #pragma unroll
            for (int k = 0; k < 2; ++k) {
                const int f = t + k * 256;
                if (f < 384) {
                    const int r = f / 12, c = f % 12;
                    __builtin_amdgcn_global_load_lds(
                        (const __attribute__((address_space(1))) void*)(src_base + (size_t)r * XCOLS + c * 4),
                        (__attribute__((address_space(3))) void*)&xs[f * 4],
                        16, 0, 0);
                }
            }
        }
        __syncthreads();   // drains global_load_lds (+ params ds_writes on rep 0)

        #pragma unroll 1
        for (int j = 0; j < NCHUNK; ++j) {
            const int b0 = bbase + j * BTILE;
            float* outp = out + (size_t)b0 * OCOLS + (size_t)g0 * OUT_DIM + l * 4;

            #pragma unroll 2
            for (int i = 0; i < 8; ++i) {
                const int b = wv * 8 + i;
                const float x0 = xb[b * (GTILE * ARITY) + 0];
                const float x1 = xb[b * (GTILE * ARITY) + 1];
                const float x2 = xb[b * (GTILE * ARITY) + 2];

                const bool n0 = x0 < 0.0f, n1 = x1 < 0.0f, n2 = x2 < 0.0f;
                const float wl0 = n0 ? -x0       : 1.0f - x0;
                const float wh0 = n0 ? 1.0f + x0 : x0;
                const float wl1 = n1 ? -x1       : 1.0f - x1;
                const float wh1 = n1 ? 1.0f + x1 : x1;
                const float wl2 = n2 ? -x2       : 1.0f - x2;
                const float wh2 = n2 ? 1.0f + x2 : x2;
                const int   vb  = (n0 ? 0 : 1) + 3 * (n1 ? 0 : 1) + 9 * (n2 ? 0 : 1);

                const float wA = wl0 * wl1, wB = wh0 * wl1, wC = wl0 * wh1, wD = wh0 * wh1;
                const float c000 = wA * wl2, c100 = wB * wl2, c010 = wC * wl2, c110 = wD * wl2;
                const float c001 = wA * wh2, c101 = wB * wh2, c011 = wC * wh2, c111 = wD * wh2;

                const u32x2* pp = reinterpret_cast<const u32x2*>(pbase + (size_t)vb * 16);
                const u32x2 r0 = pp[0];        // dv=0  (c000)
                const u32x2 r1 = pp[4];        // dv=1  (c100)
                const u32x2 r2 = pp[12];       // dv=3  (c010)
                const u32x2 r3 = pp[16];       // dv=4  (c110)
                const u32x2 r4 = pp[36];       // dv=9  (c001)
                const u32x2 r5 = pp[40];       // dv=10 (c101)
                const u32x2 r6 = pp[48];       // dv=12 (c011)
                const u32x2 r7 = pp[52];       // dv=13 (c111)

                f32x4 acc;
                { f32x4 pv = { bflo(r0.x), bfhi(r0.x), bflo(r0.y), bfhi(r0.y) }; acc  = c000 * pv; }
                { f32x4 pv = { bflo(r1.x), bfhi(r1.x), bflo(r1.y), bfhi(r1.y) }; acc += c100 * pv; }
                { f32x4 pv = { bflo(r2.x), bfhi(r2.x), bflo(r2.y), bfhi(r2.y) }; acc += c010 * pv; }
                { f32x4 pv = { bflo(r3.x), bfhi(r3.x), bflo(r3.y), bfhi(r3.y) }; acc += c110 * pv; }
                { f32x4 pv = { bflo(r4.x), bfhi(r4.x), bflo(r4.y), bfhi(r4.y) }; acc += c001 * pv; }
                { f32x4 pv = { bflo(r5.x), bfhi(r5.x), bflo(r5.y), bfhi(r5.y) }; acc += c101 * pv; }
                { f32x4 pv = { bflo(r6.x), bfhi(r6.x), bflo(r6.y), bfhi(r6.y) }; acc += c011 * pv; }
                { f32x4 pv = { bflo(r7.x), bfhi(r7.x), bflo(r7.y), bfhi(r7.y) }; acc += c111 * pv; }

                __builtin_nontemporal_store(acc,
                    reinterpret_cast<f32x4*>(outp + (size_t)b * OCOLS));
            }

            __syncthreads();   // all waves done reading xs before restage

            if (j + 1 < NCHUNK) {
                const float* src_base = X + (size_t)(bbase + (j + 1) * BTILE) * XCOLS + g0 * ARITY;
                #pragma unroll
                for (int k = 0; k < 2; ++k) {
                    const int f = t + k * 256;
                    if (f < 384) {
                        const int r = f / 12, c = f % 12;
                        __builtin_amdgcn_global_load_lds(
                            (const __attribute__((address_space(1))) void*)(src_base + (size_t)r * XCOLS + c * 4),
                            (__attribute__((address_space(3))) void*)&xs[f * 4],
                            16, 0, 0);
                    }
                }
                __syncthreads();   // staging complete before compute reads
            }
        }
    }
}

extern "C" void kernel_launch(void* const* d_in, const int* in_sizes, int n_in,
                              void* d_out, int out_size, void* d_ws, size_t ws_size,
                              hipStream_t stream) {
    const float* X = (const float*)d_in[0];   // [8192, 1536] f32
    const float* P = (const float*)d_in[1];   // [512, 27, 16] f32
    float* out = (float*)d_out;               // [8192, 8192] f32

    dim3 grid(GROUPS / GTILE, BATCH / (BTILE * NCHUNK)); // 32 x 64 = 2048
    dim3 block(256);
    lattice_interp_kernel<<<grid, block, 0, stream>>>(X, P, out);
}

// Round 16
// 62.632 us; speedup vs baseline: 4.3241x; 4.3241x over previous
//
#include <hip/hip_runtime.h>

// Problem constants (fixed by the reference)
#define BATCH   8192
#define GROUPS  512
#define ARITY   3
#define OUT_DIM 16
#define NV      27          // 3^3 vertices
#define XCOLS   (GROUPS*ARITY)      // 1536
#define OCOLS   (GROUPS*OUT_DIM)    // 8192

// R16 = R15 with the compile fix (cvt_pkrtz returns __fp16x2; bitcast to
// _Float16x2 via union). Theory unchanged — attack R14's measured hot
// pipes (VALUBusy 75.6%, SQ_LDS_BANK_CONFLICT 72.6M, HBM only 58%):
//  - fp16 d2-pair params + v_dot2_f32_f16 (f32 accum): kills the 32
//    bf16-unpack VALU ops and halves FMA instrs (16 dot2 for 32 MACs).
//  - LDS layout [d01:9][d2sel:2][o:16] u32-pairs, group stride 296 words
//    (mod 32 = 8): param gather = 4x ds_read_b128, near-uniform banks.
//  - DS instrs 11 -> 7 per KB of output.
// Keep (all A/B-proven): nt stores, g-fast grid, persistent blocks, 8/CU.
#define GTILE   8
#define BTILE   32
#define NCHUNK  8
#define BROWS   (BTILE*NCHUNK)    // 256 rows per block
#define PGS     296               // param group stride in u32 (1184B; %32 words = 8)

typedef float    f32x4 __attribute__((ext_vector_type(4)));
typedef _Float16 f16x2 __attribute__((ext_vector_type(2)));
typedef unsigned u32x4 __attribute__((ext_vector_type(4)));

__device__ __forceinline__ float fdot2(f16x2 a, f16x2 b, float c) {
#if __has_builtin(__builtin_amdgcn_fdot2)
    return __builtin_amdgcn_fdot2(a, b, c, false);
#else
    float d;
    asm("v_dot2_f32_f16 %0, %1, %2, %3" : "=v"(d) : "v"(a), "v"(b), "v"(c));
    return d;
#endif
}
__device__ __forceinline__ f16x2 h2(unsigned u) {
    union { unsigned u; f16x2 h; } c; c.u = u; return c.h;
}
__device__ __forceinline__ f16x2 pkrtz(float a, float b) {
    auto r = __builtin_amdgcn_cvt_pkrtz(a, b);   // __fp16 ext_vector(2)
    union { decltype(r) i; f16x2 o; } c; c.i = r; return c.o;
}

__global__ __launch_bounds__(256, 8) void lattice_interp_kernel(
    const float* __restrict__ X,
    const float* __restrict__ P,
    float* __restrict__ out)
{
    __shared__ float    xs[BTILE * GTILE * ARITY];  // 768 f32 = 3072 B
    __shared__ unsigned ps[GTILE * PGS];            // 9472 B

    const int t  = threadIdx.x;
    const int g0 = blockIdx.x * GTILE;      // group chunk: FAST grid dim
    const int bbase = blockIdx.y * BROWS;   // 256-row span: SLOW

    // ---- params -> LDS as fp16 d2-pairs (once per block):
    // entry(d01,d2s,o) = (P[d01+9*d2s][o], P[d01+9*d2s+9][o]) as half2;
    // u32 index within group = d01*32 + d2s*16 + o. 2304 entries = 9*256.
    {
        #pragma unroll
        for (int k = 0; k < 9; ++k) {
            const int e   = t + k * 256;        // 0..2303
            const int pgl = e / 288;
            const int rem = e % 288;
            const int vlo = (rem >> 5) + 9 * ((rem >> 4) & 1);  // d01 + 9*d2s
            const int o   = rem & 15;
            const float* Pg = P + (size_t)(g0 + pgl) * (NV * OUT_DIM) + vlo * OUT_DIM + o;
            const float lo = Pg[0];
            const float hi = Pg[9 * OUT_DIM];
            union { f16x2 h; unsigned u; } cv;
            cv.h = f16x2{(_Float16)lo, (_Float16)hi};   // RTN conversions
            ps[pgl * PGS + rem] = cv.u;
        }
    }

    // ---- stage X chunk 0: 32 rows x 24 floats = 192 float4, linear LDS
    if (t < 192) {
        const int r = t / 6, c = t % 6;
        __builtin_amdgcn_global_load_lds(
            (const __attribute__((address_space(1))) void*)(X + (size_t)(bbase + r) * XCOLS + g0 * ARITY + c * 4),
            (__attribute__((address_space(3))) void*)&xs[t * 4], 16, 0, 0);
    }
    __syncthreads();   // drains global_load_lds + params ds_writes

    const int wv = t >> 6;
    const int l  = t & 63;
    const int bs = l >> 5;          // which row of the lane-pair
    const int gl = (l >> 2) & 7;    // group-local 0..7
    const int oq = l & 3;           // output quarter

    const unsigned* pg = ps + gl * PGS + oq * 4;   // + idx*16 at runtime
    const float*    xg = xs + gl * ARITY;
    // within-block out col = gl*16 + oq*4 = (l&31)*4 -> each half-wave
    // writes one contiguous 512B segment per row.
    float* outb = out + (size_t)bbase * OCOLS + (size_t)g0 * OUT_DIM + (l & 31) * 4;

    #pragma unroll 1
    for (int j = 0; j < NCHUNK; ++j) {
        #pragma unroll 1
        for (int i = 0; i < 4; ++i) {
            const int lr = wv * 8 + i * 2 + bs;      // 0..31, 2 rows/wave-iter
            const float x0 = xg[lr * (GTILE * ARITY) + 0];
            const float x1 = xg[lr * (GTILE * ARITY) + 1];
            const float x2 = xg[lr * (GTILE * ARITY) + 2];

            // containing cell + the two nonzero hat weights per dim
            const bool n0 = x0 < 0.f, n1 = x1 < 0.f, n2 = x2 < 0.f;
            const float wlo0 = n0 ? -x0 : 1.f - x0;
            const float whi0 = n0 ? 1.f + x0 : x0;
            const float wlo1 = n1 ? -x1 : 1.f - x1;
            const float whi1 = n1 ? 1.f + x1 : x1;
            const float wlo2 = n2 ? -x2 : 1.f - x2;
            const float whi2 = n2 ? 1.f + x2 : x2;
            const int s0 = n0 ? 0 : 1, s1 = n1 ? 0 : 1, s2 = n2 ? 0 : 1;
            const int idx = 2 * (s0 + 3 * s1) + s2;    // pair-slot index, <=9

            // 4 x ds_read_b128: (d0,d1) combos at d01 + {0,1,3,4}
            const unsigned* pe = pg + idx * 16;
            const u32x4 e0 = *reinterpret_cast<const u32x4*>(pe);        // +0
            const u32x4 e1 = *reinterpret_cast<const u32x4*>(pe + 32);   // +1
            const u32x4 e2 = *reinterpret_cast<const u32x4*>(pe + 96);   // +3
            const u32x4 e3 = *reinterpret_cast<const u32x4*>(pe + 128);  // +4

            const float wA = wlo0 * wlo1, wB = whi0 * wlo1;
            const float wC = wlo0 * whi1, wD = whi0 * whi1;
            const f16x2 c0 = pkrtz(wA * wlo2, wA * whi2);
            const f16x2 c1 = pkrtz(wB * wlo2, wB * whi2);
            const f16x2 c2 = pkrtz(wC * wlo2, wC * whi2);
            const f16x2 c3 = pkrtz(wD * wlo2, wD * whi2);

            f32x4 acc;
            #pragma unroll
            for (int r = 0; r < 4; ++r) {
                float a = fdot2(c0, h2(e0[r]), 0.f);
                a = fdot2(c1, h2(e1[r]), a);
                a = fdot2(c2, h2(e2[r]), a);
                a = fdot2(c3, h2(e3[r]), a);
                acc[r] = a;
            }

            __builtin_nontemporal_store(acc,
                reinterpret_cast<f32x4*>(outb + (size_t)(j * BTILE + lr) * OCOLS));
        }

        __syncthreads();   // all waves done with xs before restage
        if (j + 1 < NCHUNK) {
            if (t < 192) {
                const int r = t / 6, c = t % 6;
                __builtin_amdgcn_global_load_lds(
                    (const __attribute__((address_space(1))) void*)(X + (size_t)(bbase + (j + 1) * BTILE + r) * XCOLS + g0 * ARITY + c * 4),
                    (__attribute__((address_space(3))) void*)&xs[t * 4], 16, 0, 0);
            }
            __syncthreads();
        }
    }
}

extern "C" void kernel_launch(void* const* d_in, const int* in_sizes, int n_in,
                              void* d_out, int out_size, void* d_ws, size_t ws_size,
                              hipStream_t stream) {
    const float* X = (const float*)d_in[0];   // [8192, 1536] f32
    const float* P = (const float*)d_in[1];   // [512, 27, 16] f32
    float* out = (float*)d_out;               // [8192, 8192] f32

    dim3 grid(GROUPS / GTILE, BATCH / BROWS); // 64 x 32 = 2048 (g fast)
    dim3 block(256);
    lattice_interp_kernel<<<grid, block, 0, stream>>>(X, P, out);
}

// Round 17
// 60.633 us; speedup vs baseline: 4.4667x; 1.0330x over previous
//
#include <hip/hip_runtime.h>

// Problem constants (fixed by the reference)
#define BATCH   8192
#define GROUPS  512
#define ARITY   3
#define OUT_DIM 16
#define NV      27          // 3^3 vertices
#define XCOLS   (GROUPS*ARITY)      // 1536
#define OCOLS   (GROUPS*OUT_DIM)    // 8192

// R17 = R11 restored (best: 60.0us). Final structure, all levers A/B-proven:
//  - 8-corner multilinear gather (only containing-cell vertices nonzero)
//  - params bf16 in LDS, padded group stride (PSTRIDE=444), ds_read_b64 x8
//  - X staged via global_load_lds (16B), linear LDS
//  - nontemporal f32x4 stores, 1KB contiguous per wave-instr
//    (nt > plain: +10us and +18us in two A/Bs)
//  - g-fast grid (DRAM row locality across co-resident blocks: +10us)
//  - persistent blocks: 2048 = exactly 8/CU, one residency round,
//    params staged once, NCHUNK=4 b-chunks per block
// Corridor evidence (R10/R11/R12/R13/R16 = 62.5/60.0/61.8/78.3/62.6) says
// the binding constraint is the chunked nt-write stream (~4.4-5 TB/s at
// the MCs); VALU-halving, bank-uniformization, and barrier-removal all
// null. ~60us = practical roofline for this op shape.
#define BTILE 32
#define NCHUNK 4
#define GTILE 16
#define PSTRIDE 444     // bf16 elems per group (432 + 12 pad)

typedef float    f32x4 __attribute__((ext_vector_type(4)));
typedef unsigned u32x2 __attribute__((ext_vector_type(2)));

__device__ __forceinline__ unsigned cvt_pk_bf16(float lo, float hi) {
    unsigned r;
    asm("v_cvt_pk_bf16_f32 %0, %1, %2" : "=v"(r) : "v"(lo), "v"(hi));
    return r;
}
__device__ __forceinline__ float bflo(unsigned u) {
    union { unsigned u; float f; } c; c.u = u << 16; return c.f;
}
__device__ __forceinline__ float bfhi(unsigned u) {
    union { unsigned u; float f; } c; c.u = u & 0xffff0000u; return c.f;
}

__global__ __launch_bounds__(256, 8) void lattice_interp_kernel(
    const float* __restrict__ X,
    const float* __restrict__ P,
    float* __restrict__ out)
{
    __shared__ float xs[BTILE * GTILE * ARITY];        // 1536 f32 = 6144 B
    __shared__ unsigned short ps[GTILE * PSTRIDE];     // 7104 bf16 = 14208 B

    const int t  = threadIdx.x;
    const int g0 = blockIdx.x * GTILE;              // group chunk: FAST dim
    const int bbase = blockIdx.y * (BTILE * NCHUNK); // 128-batch span: SLOW

    // ---- stage params for 16 groups as bf16 (ONCE per block):
    // 1728 float4 -> cvt_pk -> ds_write_b64. group pgl at elem pgl*444.
    {
        const float4* src = reinterpret_cast<const float4*>(P + (size_t)g0 * (NV * OUT_DIM));
        #pragma unroll
        for (int k = 0; k < 7; ++k) {
            const int f = t + k * 256;
            if (f < 1728) {
                const float4 v = src[f];
                const int pgl = f / 108;          // 108 float4 per group
                const int rem = f - pgl * 108;
                u32x2 w;
                w.x = cvt_pk_bf16(v.x, v.y);
                w.y = cvt_pk_bf16(v.z, v.w);
                *reinterpret_cast<u32x2*>(&ps[pgl * PSTRIDE + rem * 4]) = w;
            }
        }
    }

    // ---- stage X chunk 0: rows [bbase, bbase+32) cols [g0*3, g0*3+48).
    {
        const float* src_base = X + (size_t)bbase * XCOLS + g0 * ARITY;
        #pragma unroll
        for (int k = 0; k < 2; ++k) {
            const int f = t + k * 256;
            if (f < 384) {
                const int r = f / 12, c = f % 12;
                __builtin_amdgcn_global_load_lds(
                    (const __attribute__((address_space(1))) void*)(src_base + (size_t)r * XCOLS + c * 4),
                    (__attribute__((address_space(3))) void*)&xs[f * 4],
                    16, 0, 0);
            }
        }
    }

    __syncthreads();   // drains global_load_lds (vmcnt) + ds_writes (lgkmcnt)

    const int wv = t >> 6;
    const int l  = t & 63;
    const int gl = l >> 2;    // group-local 0..15
    const int oq = l & 3;     // which float4 of the 16 outputs

    const unsigned short* pbase = ps + gl * PSTRIDE + oq * 4;  // + vb*16 at runtime
    const float* xb = xs + gl * ARITY;

    #pragma unroll 1
    for (int j = 0; j < NCHUNK; ++j) {
        const int b0 = bbase + j * BTILE;
        // within-block out col = gl*16 + oq*4 = 4*l -> wave writes 1KB contiguous
        float* outp = out + (size_t)b0 * OCOLS + (size_t)g0 * OUT_DIM + l * 4;

        #pragma unroll 2
        for (int i = 0; i < 8; ++i) {
            const int b = wv * 8 + i;
            const float x0 = xb[b * (GTILE * ARITY) + 0];
            const float x1 = xb[b * (GTILE * ARITY) + 1];
            const float x2 = xb[b * (GTILE * ARITY) + 2];

            // containing cell per dim; lower/upper hat weights (3rd == 0)
            const bool n0 = x0 < 0.0f, n1 = x1 < 0.0f, n2 = x2 < 0.0f;
            const float wl0 = n0 ? -x0       : 1.0f - x0;
            const float wh0 = n0 ? 1.0f + x0 : x0;
            const float wl1 = n1 ? -x1       : 1.0f - x1;
            const float wh1 = n1 ? 1.0f + x1 : x1;
            const float wl2 = n2 ? -x2       : 1.0f - x2;
            const float wh2 = n2 ? 1.0f + x2 : x2;
            const int   vb  = (n0 ? 0 : 1) + 3 * (n1 ? 0 : 1) + 9 * (n2 ? 0 : 1);

            // 8 corner weights
            const float wA = wl0 * wl1, wB = wh0 * wl1, wC = wl0 * wh1, wD = wh0 * wh1;
            const float c000 = wA * wl2, c100 = wB * wl2, c010 = wC * wl2, c110 = wD * wl2;
            const float c001 = wA * wh2, c101 = wB * wh2, c011 = wC * wh2, c111 = wD * wh2;

            // one runtime base + 8 immediate-offset ds_read_b64 (4 bf16 each)
            const u32x2* pp = reinterpret_cast<const u32x2*>(pbase + (size_t)vb * 16);
            const u32x2 r0 = pp[0];        // dv=0  (c000)
            const u32x2 r1 = pp[4];        // dv=1  (c100)
            const u32x2 r2 = pp[12];       // dv=3  (c010)
            const u32x2 r3 = pp[16];       // dv=4  (c110)
            const u32x2 r4 = pp[36];       // dv=9  (c001)
            const u32x2 r5 = pp[40];       // dv=10 (c101)
            const u32x2 r6 = pp[48];       // dv=12 (c011)
            const u32x2 r7 = pp[52];       // dv=13 (c111)

            f32x4 acc;
            { f32x4 pv = { bflo(r0.x), bfhi(r0.x), bflo(r0.y), bfhi(r0.y) }; acc  = c000 * pv; }
            { f32x4 pv = { bflo(r1.x), bfhi(r1.x), bflo(r1.y), bfhi(r1.y) }; acc += c100 * pv; }
            { f32x4 pv = { bflo(r2.x), bfhi(r2.x), bflo(r2.y), bfhi(r2.y) }; acc += c010 * pv; }
            { f32x4 pv = { bflo(r3.x), bfhi(r3.x), bflo(r3.y), bfhi(r3.y) }; acc += c110 * pv; }
            { f32x4 pv = { bflo(r4.x), bfhi(r4.x), bflo(r4.y), bfhi(r4.y) }; acc += c001 * pv; }
            { f32x4 pv = { bflo(r5.x), bfhi(r5.x), bflo(r5.y), bfhi(r5.y) }; acc += c101 * pv; }
            { f32x4 pv = { bflo(r6.x), bfhi(r6.x), bflo(r6.y), bfhi(r6.y) }; acc += c011 * pv; }
            { f32x4 pv = { bflo(r7.x), bfhi(r7.x), bflo(r7.y), bfhi(r7.y) }; acc += c111 * pv; }

            __builtin_nontemporal_store(acc,
                reinterpret_cast<f32x4*>(outp + (size_t)b * OCOLS));
        }

        __syncthreads();   // all waves done reading xs before restage

        if (j + 1 < NCHUNK) {
            const float* src_base = X + (size_t)(bbase + (j + 1) * BTILE) * XCOLS + g0 * ARITY;
            #pragma unroll
            for (int k = 0; k < 2; ++k) {
                const int f = t + k * 256;
                if (f < 384) {
                    const int r = f / 12, c = f % 12;
                    __builtin_amdgcn_global_load_lds(
                        (const __attribute__((address_space(1))) void*)(src_base + (size_t)r * XCOLS + c * 4),
                        (__attribute__((address_space(3))) void*)&xs[f * 4],
                        16, 0, 0);
                }
            }
            __syncthreads();   // staging complete before compute reads
        }
    }
}

extern "C" void kernel_launch(void* const* d_in, const int* in_sizes, int n_in,
                              void* d_out, int out_size, void* d_ws, size_t ws_size,
                              hipStream_t stream) {
    const float* X = (const float*)d_in[0];   // [8192, 1536] f32
    const float* P = (const float*)d_in[1];   // [512, 27, 16] f32
    float* out = (float*)d_out;               // [8192, 8192] f32

    dim3 grid(GROUPS / GTILE, BATCH / (BTILE * NCHUNK)); // 32 x 64 = 2048
    dim3 block(256);
    lattice_interp_kernel<<<grid, block, 0, stream>>>(X, P, out);
}